// Round 3
// baseline (1887.489 us; speedup 1.0000x reference)
//
#include <hip/hip_runtime.h>
#include <stdint.h>

typedef unsigned short u16;
typedef __attribute__((ext_vector_type(4))) float f32x4;
typedef __attribute__((ext_vector_type(8))) __bf16 bf16x8;
typedef __attribute__((ext_vector_type(4))) u16 u16x4;

#define B_  8192
#define D_  4096
#define C4_ 4096
#define C_  1024
#define K_  8192
#define BM  128
#define BN  128

__device__ __forceinline__ void load_lds16(const void* g, void* l) {
  __builtin_amdgcn_global_load_lds(
      (const __attribute__((address_space(1))) unsigned int*)g,
      (__attribute__((address_space(3))) unsigned int*)l, 16, 0, 0);
}

__device__ __forceinline__ u16 f2bf(float v) {
  unsigned int u = __float_as_uint(v);
  return (u16)((u + 0x7FFFu + ((u >> 16) & 1u)) >> 16);   // RNE
}
__device__ __forceinline__ float bf2f(u16 u) {
  return __uint_as_float(((unsigned int)u) << 16);
}
__device__ __forceinline__ unsigned int fkey(float x) {   // monotone float->uint
  unsigned int u = __float_as_uint(x);
  return u ^ (((unsigned int)(((int)u) >> 31)) | 0x80000000u);
}

// ------- split-bf16 GEMM mainloop: T2 swizzle + T3 double-buffer ----------
// A: [M][K] hi/lo bf16 row-major (K contiguous). B: [N][K] hi/lo bf16 (B^T).
// 128x128 tile, BK=64, 256 threads = 4 waves (2x2), 4x4 16x16 frags/wave.
// acc = Ah*Bh + Al*Bh + Ah*Bl  (~17-bit effective input mantissa).
// LDS: 2 parities x 4 arrays x [128][64] u16 = 128 KB dynamic.
// Schedule (T3 minimum 2-phase, verified m248v2):
//   prologue: STAGE(p0, t0); barrier;
//   loop t:   STAGE(p^1, t+1); compute(p); barrier;
// The end-of-iter barrier's implicit vmcnt(0) drains NEXT-tile loads that
// had the whole compute phase in flight; buffer reuse is ordered by the
// same barrier (all ds_reads of buf[p] retire before it).
__device__ __forceinline__ void stage_tile(
    const u16* __restrict__ Ah, const u16* __restrict__ Al,
    const u16* __restrict__ Bh, const u16* __restrict__ Bl,
    int K, int rowA0, int rowB0, int k0, u16* lds, int parity,
    int w, int lane) {
  u16* dst = lds + parity * 32768;
  const int rstage = w * 8 + (lane >> 3);   // row within 32-row stage chunk
  // pre-swizzled global 16B-slot: lane loads slot (lane&7)^(row&7), so that
  // LDS[row][slot s] = global slot s^(row&7). row&7 == lane>>3 here.
  const int estage = (((lane & 7) ^ (lane >> 3)) << 3);
#pragma unroll
  for (int c = 0; c < 4; ++c) {
    const int r = c * 32 + rstage;
    const size_t ga = (size_t)(rowA0 + r) * K + (k0 + estage);
    const size_t gb = (size_t)(rowB0 + r) * K + (k0 + estage);
    const int lo = (c * 32 + w * 8) * 64;  // wave-uniform LDS base
    load_lds16(Ah + ga, dst + lo);
    load_lds16(Al + ga, dst + 8192 + lo);
    load_lds16(Bh + gb, dst + 16384 + lo);
    load_lds16(Bl + gb, dst + 24576 + lo);
  }
}

__device__ __forceinline__ void mfma_mainloop(
    const u16* __restrict__ Ah, const u16* __restrict__ Al,
    const u16* __restrict__ Bh, const u16* __restrict__ Bl,
    int K, int rowA0, int rowB0, u16* lds, f32x4 acc[4][4]) {
  const int tid = threadIdx.x;
  const int lane = tid & 63;
  const int w = tid >> 6;
  const int wr = w >> 1, wc = w & 1;

#pragma unroll
  for (int m = 0; m < 4; ++m)
#pragma unroll
    for (int n = 0; n < 4; ++n) acc[m][n] = (f32x4){0.f, 0.f, 0.f, 0.f};

  const int nt = K >> 6;
  stage_tile(Ah, Al, Bh, Bl, K, rowA0, rowB0, 0, lds, 0, w, lane);
  __syncthreads();

  for (int t = 0; t < nt; ++t) {
    const int p = t & 1;
    if (t + 1 < nt)
      stage_tile(Ah, Al, Bh, Bl, K, rowA0, rowB0, (t + 1) << 6, lds, p ^ 1, w, lane);

    const u16* As_h = lds + p * 32768;
    const u16* As_l = As_h + 8192;
    const u16* Bs_h = As_h + 16384;
    const u16* Bs_l = As_h + 24576;
#pragma unroll
    for (int ks = 0; ks < 2; ++ks) {
      bf16x8 ah[4], al[4], bh[4], bl[4];
      // fragment rows are wr*64 + m*16 + (lane&15): row&7 == lane&7 for all
      // m, so the swizzled 16B slot is (ks*4 + (lane>>4)) ^ (lane&7).
      const int kof = (((ks * 4 + (lane >> 4)) ^ (lane & 7)) << 3);
#pragma unroll
      for (int m = 0; m < 4; ++m) {
        const int ra = (wr * 64 + m * 16 + (lane & 15)) * 64 + kof;
        ah[m] = *(const bf16x8*)(As_h + ra);
        al[m] = *(const bf16x8*)(As_l + ra);
      }
#pragma unroll
      for (int n = 0; n < 4; ++n) {
        const int rb = (wc * 64 + n * 16 + (lane & 15)) * 64 + kof;
        bh[n] = *(const bf16x8*)(Bs_h + rb);
        bl[n] = *(const bf16x8*)(Bs_l + rb);
      }
#pragma unroll
      for (int m = 0; m < 4; ++m)
#pragma unroll
        for (int n = 0; n < 4; ++n) {
          acc[m][n] = __builtin_amdgcn_mfma_f32_16x16x32_bf16(ah[m], bh[n], acc[m][n], 0, 0, 0);
          acc[m][n] = __builtin_amdgcn_mfma_f32_16x16x32_bf16(al[m], bh[n], acc[m][n], 0, 0, 0);
          acc[m][n] = __builtin_amdgcn_mfma_f32_16x16x32_bf16(ah[m], bl[n], acc[m][n], 0, 0, 0);
        }
    }
    __syncthreads();
  }
}

// -------- GEMM1: h = silu(x@W1 + b1), write h as bf16 hi/lo ---------------
__global__ __launch_bounds__(256, 2)
void k_gemm1(const u16* __restrict__ xh, const u16* __restrict__ xl,
             const u16* __restrict__ w1h, const u16* __restrict__ w1l,
             const float* __restrict__ b1,
             u16* __restrict__ hh, u16* __restrict__ hl) {
  extern __shared__ u16 lds[];
  const int nbn = C4_ / BN;
  const int bm = blockIdx.x / nbn, bn = blockIdx.x % nbn;
  f32x4 acc[4][4];
  mfma_mainloop(xh, xl, w1h, w1l, D_, bm * BM, bn * BN, lds, acc);
  const int lane = threadIdx.x & 63, w = threadIdx.x >> 6;
  const int wr = w >> 1, wc = w & 1;
#pragma unroll
  for (int m = 0; m < 4; ++m)
#pragma unroll
    for (int n = 0; n < 4; ++n)
#pragma unroll
      for (int j = 0; j < 4; ++j) {
        const int rg = bm * BM + wr * 64 + m * 16 + (lane >> 4) * 4 + j;
        const int cg = bn * BN + wc * 64 + n * 16 + (lane & 15);
        const float v = acc[m][n][j] + b1[cg];
        const float s = v / (1.f + __expf(-v));
        const size_t o = (size_t)rg * C4_ + cg;
        const u16 hi = f2bf(s);
        hh[o] = hi;
        hl[o] = f2bf(s - bf2f(hi));
      }
}

// -------- GEMM2: z = h@W2 + b2, write z f32 + bf16 hi/lo ------------------
__global__ __launch_bounds__(256, 2)
void k_gemm2(const u16* __restrict__ ah, const u16* __restrict__ al,
             const u16* __restrict__ bh, const u16* __restrict__ bl,
             const float* __restrict__ b2,
             float* __restrict__ zf, u16* __restrict__ zh, u16* __restrict__ zl) {
  extern __shared__ u16 lds[];
  const int nbn = C_ / BN;
  const int bm = blockIdx.x / nbn, bn = blockIdx.x % nbn;
  f32x4 acc[4][4];
  mfma_mainloop(ah, al, bh, bl, C4_, bm * BM, bn * BN, lds, acc);
  const int lane = threadIdx.x & 63, w = threadIdx.x >> 6;
  const int wr = w >> 1, wc = w & 1;
#pragma unroll
  for (int m = 0; m < 4; ++m)
#pragma unroll
    for (int n = 0; n < 4; ++n)
#pragma unroll
      for (int j = 0; j < 4; ++j) {
        const int rg = bm * BM + wr * 64 + m * 16 + (lane >> 4) * 4 + j;
        const int cg = bn * BN + wc * 64 + n * 16 + (lane & 15);
        const float v = acc[m][n][j] + b2[cg];
        const size_t o = (size_t)rg * C_ + cg;
        zf[o] = v;
        const u16 hi = f2bf(v);
        zh[o] = hi;
        zl[o] = f2bf(v - bf2f(hi));
      }
}

// -------- GEMM3: s = ||e_k||^2 - 2 z.e_k, fused row-argmin ----------------
__global__ __launch_bounds__(256, 2)
void k_gemm3(const u16* __restrict__ zh, const u16* __restrict__ zl,
             const u16* __restrict__ eh, const u16* __restrict__ el,
             const float* __restrict__ norms, unsigned long long* __restrict__ am) {
  extern __shared__ u16 lds[];
  const int nbn = K_ / BN;
  const int bm = blockIdx.x / nbn, bn = blockIdx.x % nbn;
  f32x4 acc[4][4];
  mfma_mainloop(zh, zl, eh, el, C_, bm * BM, bn * BN, lds, acc);
  const int lane = threadIdx.x & 63, w = threadIdx.x >> 6;
  const int wr = w >> 1, wc = w & 1;
#pragma unroll
  for (int m = 0; m < 4; ++m) {
#pragma unroll
    for (int j = 0; j < 4; ++j) {
      float best = 3.4e38f;
      int bestn = 0x7fffffff;
#pragma unroll
      for (int n = 0; n < 4; ++n) {
        const int cg = bn * BN + wc * 64 + n * 16 + (lane & 15);
        const float s = norms[cg] - 2.f * acc[m][n][j];
        if (s < best) { best = s; bestn = cg; }
      }
      // reduce across the 16 lanes (lane&15) holding this row
#pragma unroll
      for (int off = 1; off <= 8; off <<= 1) {
        const float ob = __shfl_xor(best, off, 64);
        const int obn = __shfl_xor(bestn, off, 64);
        if (ob < best || (ob == best && obn < bestn)) { best = ob; bestn = obn; }
      }
      if ((lane & 15) == 0) {
        const int rg = bm * BM + wr * 64 + m * 16 + (lane >> 4) * 4 + j;
        const unsigned long long key =
            ((unsigned long long)fkey(best) << 32) | (unsigned int)bestn;
        atomicMin(&am[rg], key);
      }
    }
  }
}

// -------- prep kernels ----------------------------------------------------
__global__ void k_split(const float4* __restrict__ in, size_t n4,
                        u16* __restrict__ hi, u16* __restrict__ lo) {
  size_t i = (size_t)blockIdx.x * blockDim.x + threadIdx.x;
  const size_t stride = (size_t)gridDim.x * blockDim.x;
  for (; i < n4; i += stride) {
    const float4 v = in[i];
    const float vv[4] = {v.x, v.y, v.z, v.w};
    u16x4 h, l;
#pragma unroll
    for (int j = 0; j < 4; ++j) {
      const u16 a = f2bf(vv[j]);
      h[j] = a;
      l[j] = f2bf(vv[j] - bf2f(a));
    }
    *(u16x4*)(hi + i * 4) = h;
    *(u16x4*)(lo + i * 4) = l;
  }
}

template <bool WF32>
__global__ void k_tsplit(const float* __restrict__ in, int R, int Cc,
                         u16* __restrict__ hiT, u16* __restrict__ loT,
                         float* __restrict__ f32T) {
  __shared__ float t[32][33];
  const int c0 = blockIdx.x * 32, r0 = blockIdx.y * 32;
  const int tx = threadIdx.x, ty = threadIdx.y;
#pragma unroll
  for (int i = 0; i < 4; ++i)
    t[ty + i * 8][tx] = in[(size_t)(r0 + ty + i * 8) * Cc + (c0 + tx)];
  __syncthreads();
#pragma unroll
  for (int i = 0; i < 4; ++i) {
    const int orow = c0 + ty + i * 8;
    const int ocol = r0 + tx;
    const float v = t[tx][ty + i * 8];
    const size_t o = (size_t)orow * R + ocol;
    const u16 hi = f2bf(v);
    hiT[o] = hi;
    loT[o] = f2bf(v - bf2f(hi));
    if (WF32) f32T[o] = v;
  }
}

__global__ void k_norms(const float* __restrict__ embed, float* __restrict__ norms) {
  const int k = blockIdx.x * blockDim.x + threadIdx.x;
  if (k >= K_) return;
  double s = 0.0;
  for (int c = 0; c < C_; ++c) {
    const float v = embed[(size_t)c * K_ + k];
    s += (double)v * (double)v;
  }
  norms[k] = (float)s;
}

__global__ void k_init(unsigned long long* __restrict__ am, double* __restrict__ dacc) {
  const int i = blockIdx.x * blockDim.x + threadIdx.x;
  if (i < B_) am[i] = 0xFFFFFFFFFFFFFFFFull;
  if (i == 0) *dacc = 0.0;
}

// -------- finalize: gather + LayerNorm + commitment partial ---------------
__global__ __launch_bounds__(256)
void k_finalize(const unsigned long long* __restrict__ am,
                const float* __restrict__ embT, const float* __restrict__ zf,
                const float* __restrict__ gamma, const float* __restrict__ beta,
                float* __restrict__ out, double* __restrict__ dacc) {
  const int row = blockIdx.x;
  const int tid = threadIdx.x;
  const int lane = tid & 63, w = tid >> 6;
  const int idx = (int)(am[row] & 0xFFFFFFFFull);

  const float4 e4 = *(const float4*)(embT + (size_t)idx * C_ + tid * 4);
  float s1 = e4.x + e4.y + e4.z + e4.w;
  float s2 = e4.x * e4.x + e4.y * e4.y + e4.z * e4.z + e4.w * e4.w;
#pragma unroll
  for (int off = 32; off >= 1; off >>= 1) {
    s1 += __shfl_xor(s1, off, 64);
    s2 += __shfl_xor(s2, off, 64);
  }
  __shared__ float r1[4], r2[4], rd[4];
  if (lane == 0) { r1[w] = s1; r2[w] = s2; }
  __syncthreads();
  const float S1 = r1[0] + r1[1] + r1[2] + r1[3];
  const float S2 = r2[0] + r2[1] + r2[2] + r2[3];
  const float mu = S1 * (1.f / C_);
  const float var = S2 * (1.f / C_) - mu * mu;
  const float inv = 1.f / sqrtf(var + 1e-5f);

  const float4 z4 = *(const float4*)(zf + (size_t)row * C_ + tid * 4);
  const float4 g4 = *(const float4*)(gamma + tid * 4);
  const float4 b4 = *(const float4*)(beta + tid * 4);
  float4 o4;
  o4.x = (e4.x - mu) * inv * g4.x + b4.x;
  o4.y = (e4.y - mu) * inv * g4.y + b4.y;
  o4.z = (e4.z - mu) * inv * g4.z + b4.z;
  o4.w = (e4.w - mu) * inv * g4.w + b4.w;
  *(float4*)(out + (size_t)row * C_ + tid * 4) = o4;

  const float dx = e4.x - z4.x, dy = e4.y - z4.y, dz = e4.z - z4.z, dw = e4.w - z4.w;
  float d = dx * dx + dy * dy + dz * dz + dw * dw;
#pragma unroll
  for (int off = 32; off >= 1; off >>= 1) d += __shfl_xor(d, off, 64);
  __syncthreads();
  if (lane == 0) rd[w] = d;
  __syncthreads();
  if (tid == 0) atomicAdd(dacc, (double)(rd[0] + rd[1] + rd[2] + rd[3]));
}

__global__ void k_wdiff(const double* __restrict__ dacc, float* __restrict__ out) {
  out[(size_t)B_ * C_] = (float)(0.01 * (*dacc) / ((double)B_ * (double)C_));
}

// ---------------------------------------------------------------------------
extern "C" void kernel_launch(void* const* d_in, const int* in_sizes, int n_in,
                              void* d_out, int out_size, void* d_ws, size_t ws_size,
                              hipStream_t stream) {
  const float* x     = (const float*)d_in[0];
  const float* W1    = (const float*)d_in[1];
  const float* b1    = (const float*)d_in[2];
  const float* W2    = (const float*)d_in[3];
  const float* b2    = (const float*)d_in[4];
  const float* gamma = (const float*)d_in[5];
  const float* beta  = (const float*)d_in[6];
  const float* embed = (const float*)d_in[7];
  float* out = (float*)d_out;

  char* ws = (char*)d_ws;
  const size_t MB64 = 67108864ull;  // 8192*4096*2
  u16* xh  = (u16*)(ws);
  u16* xl  = (u16*)(ws + MB64);
  u16* w1h = (u16*)(ws + 2 * MB64);
  u16* w1l = (u16*)(ws + 2 * MB64 + 33554432ull);
  u16* hh  = (u16*)(ws + 3 * MB64);
  u16* hl  = (u16*)(ws + 4 * MB64);
  u16* w2h = (u16*)(ws);
  u16* w2l = (u16*)(ws + 8388608ull);
  float* zf = (float*)(ws + 16777216ull);
  u16* zh  = (u16*)(ws + MB64);
  u16* zl  = (u16*)(ws + MB64 + 16777216ull);
  float* norms = (float*)(ws + MB64 + 33554432ull);
  unsigned long long* am = (unsigned long long*)(ws + MB64 + 33554432ull + 65536ull);
  double* dacc = (double*)(ws + MB64 + 33554432ull + 131072ull);
  float* embT = (float*)(ws + 2 * MB64);
  u16* eh  = (u16*)(ws + 2 * MB64 + 33554432ull);
  u16* el  = (u16*)(ws + 2 * MB64 + 50331648ull);

  // allow 128 KB dynamic LDS for the GEMM kernels (idempotent, host-side)
  (void)hipFuncSetAttribute((const void*)k_gemm1,
                            hipFuncAttributeMaxDynamicSharedMemorySize, 131072);
  (void)hipFuncSetAttribute((const void*)k_gemm2,
                            hipFuncAttributeMaxDynamicSharedMemorySize, 131072);
  (void)hipFuncSetAttribute((const void*)k_gemm3,
                            hipFuncAttributeMaxDynamicSharedMemorySize, 131072);

  // 1. split x -> xh/xl
  k_split<<<2048, 256, 0, stream>>>((const float4*)x, (size_t)B_ * D_ / 4, xh, xl);
  // 2. W1 [D][4C] -> W1T hi/lo [4C][D]
  k_tsplit<false><<<dim3(C4_ / 32, D_ / 32), dim3(32, 8), 0, stream>>>(W1, D_, C4_, w1h, w1l, nullptr);
  // 3. GEMM1 (+bias+SiLU+split)
  k_gemm1<<<(B_ / BM) * (C4_ / BN), 256, 131072, stream>>>(xh, xl, w1h, w1l, b1, hh, hl);
  // 4. W2 [4C][C] -> W2T hi/lo [C][4C]  (region A is free now)
  k_tsplit<false><<<dim3(C_ / 32, C4_ / 32), dim3(32, 8), 0, stream>>>(W2, C4_, C_, w2h, w2l, nullptr);
  // 5. GEMM2 (+bias, write z f32 + hi/lo)
  k_gemm2<<<(B_ / BM) * (C_ / BN), 256, 131072, stream>>>(hh, hl, w2h, w2l, b2, zf, zh, zl);
  // 6. embed [C][K] -> embT f32 + hi/lo [K][C]  (regions C/D free now)
  k_tsplit<true><<<dim3(K_ / 32, C_ / 32), dim3(32, 8), 0, stream>>>(embed, C_, K_, eh, el, embT);
  // 7. codebook column norms (f64 accumulate)
  k_norms<<<K_ / 256, 256, 0, stream>>>(embed, norms);
  // 8. init argmin keys + diff accumulator
  k_init<<<B_ / 256, 256, 0, stream>>>(am, dacc);
  // 9. GEMM3 + fused argmin
  k_gemm3<<<(B_ / BM) * (K_ / BN), 256, 131072, stream>>>(zh, zl, eh, el, norms, am);
  // 10. gather + LayerNorm + commitment partial sums
  k_finalize<<<B_, 256, 0, stream>>>(am, embT, zf, gamma, beta, out, dacc);
  // 11. scalar diff output
  k_wdiff<<<1, 1, 0, stream>>>(dacc, out);
}

// Round 4
// 1600.032 us; speedup vs baseline: 1.1797x; 1.1797x over previous
//
#include <hip/hip_runtime.h>
#include <stdint.h>

typedef unsigned short u16;
typedef __attribute__((ext_vector_type(4))) float f32x4;
typedef __attribute__((ext_vector_type(8))) __bf16 bf16x8;
typedef __attribute__((ext_vector_type(4))) u16 u16x4;

#define B_  8192
#define D_  4096
#define C4_ 4096
#define C_  1024
#define K_  8192
#define BM  128
#define BN  128

__device__ __forceinline__ void load_lds16(const void* g, void* l) {
  __builtin_amdgcn_global_load_lds(
      (const __attribute__((address_space(1))) unsigned int*)g,
      (__attribute__((address_space(3))) unsigned int*)l, 16, 0, 0);
}

__device__ __forceinline__ u16 f2bf(float v) {
  unsigned int u = __float_as_uint(v);
  return (u16)((u + 0x7FFFu + ((u >> 16) & 1u)) >> 16);   // RNE
}
__device__ __forceinline__ float bf2f(u16 u) {
  return __uint_as_float(((unsigned int)u) << 16);
}
__device__ __forceinline__ unsigned int fkey(float x) {   // monotone float->uint
  unsigned int u = __float_as_uint(x);
  return u ^ (((unsigned int)(((int)u) >> 31)) | 0x80000000u);
}

// ---- split-bf16 GEMM mainloop: T2 swizzle + BK=32 ring + counted vmcnt ----
// A: [M][K] hi/lo bf16 row-major (K contiguous). B: [N][K] hi/lo bf16 (B^T).
// 128x128 tile, 256 threads = 4 waves (2x2), 4x4 16x16 frags/wave.
// acc = Ah*Bh + Al*Bh + Ah*Bl  (~17-bit effective input mantissa).
//
// LDS: 2 parity buffers x 4 arrays x [128][32] u16 = 64 KB total -> 2
// blocks/CU stay resident (the R3 dbuf at 128 KB dropped to 1 block/CU and
// regressed). Rows are 64 B = 4 x 16B slots; swizzle: LDS[row][s] holds
// global slot s^(row&3) (pre-swizzled global source, swizzled ds_read —
// both sides). Each fragment ds_read_b128 covers a full 1 KB row-group,
// every 16B slot exactly once -> minimal bank aliasing.
//
// Schedule (T4 counted vmcnt, never 0 in the loop):
//   prologue: STAGE(p0,t0); STAGE(p1,t1)        [8 loads each]
//   iter t:   vmcnt(8); s_barrier;              [tile t's 8 landed]
//             compute(p_t); s_barrier;          [readers done]
//             STAGE(p_t, t+2)                   [refill freed buffer]
//   epilogue: vmcnt(0); s_barrier; compute(last)
// Tile t+2's loads are issued at end of iter t and waited at top of iter
// t+2 — a full compute phase in flight. Raw asm s_barrier (with "memory"
// clobber) so the compiler cannot legalize a vmcnt(0) drain in front.
__device__ __forceinline__ void stage32(
    const u16* __restrict__ Ah, const u16* __restrict__ Al,
    const u16* __restrict__ Bh, const u16* __restrict__ Bl,
    int K, int rowA0, int rowB0, int k0, u16* lds, int parity,
    int w, int lane) {
  u16* dst = lds + parity * 16384;
  const int rlo = lane >> 2;                        // 0..15 row within chunk
  const int gs8 = (((lane & 3) ^ (rlo & 3)) << 3);  // pre-swizzled 16B slot
#pragma unroll
  for (int c = 0; c < 2; ++c) {
    const int chunk = c * 4 + w;                    // 8 chunks of 16 rows
    const int row = chunk * 16 + rlo;
    const size_t ga = (size_t)(rowA0 + row) * K + (k0 + gs8);
    const size_t gb = (size_t)(rowB0 + row) * K + (k0 + gs8);
    const int lo = chunk * 512;                     // u16, wave-uniform
    load_lds16(Ah + ga, dst + lo);
    load_lds16(Al + ga, dst + 4096 + lo);
    load_lds16(Bh + gb, dst + 8192 + lo);
    load_lds16(Bl + gb, dst + 12288 + lo);
  }
}

__device__ __forceinline__ void compute32(
    const u16* lds, int parity, int wr, int wc, int lane, f32x4 acc[4][4]) {
  const u16* base = lds + parity * 16384;
  // fragment row&3 == lane&3, wanted k-slot == lane>>4; stored at slot
  // (lane>>4)^(row&3)  (same involution as the staging pre-swizzle).
  const int kslot8 = ((((lane >> 4) & 3) ^ (lane & 3)) << 3);
  bf16x8 ah[4], al[4], bh[4], bl[4];
#pragma unroll
  for (int m = 0; m < 4; ++m) {
    const int ra = (wr * 64 + m * 16 + (lane & 15)) * 32 + kslot8;
    ah[m] = *(const bf16x8*)(base + ra);
    al[m] = *(const bf16x8*)(base + 4096 + ra);
  }
#pragma unroll
  for (int n = 0; n < 4; ++n) {
    const int rb = (wc * 64 + n * 16 + (lane & 15)) * 32 + kslot8;
    bh[n] = *(const bf16x8*)(base + 8192 + rb);
    bl[n] = *(const bf16x8*)(base + 12288 + rb);
  }
#pragma unroll
  for (int m = 0; m < 4; ++m)
#pragma unroll
    for (int n = 0; n < 4; ++n) {
      acc[m][n] = __builtin_amdgcn_mfma_f32_16x16x32_bf16(ah[m], bh[n], acc[m][n], 0, 0, 0);
      acc[m][n] = __builtin_amdgcn_mfma_f32_16x16x32_bf16(al[m], bh[n], acc[m][n], 0, 0, 0);
      acc[m][n] = __builtin_amdgcn_mfma_f32_16x16x32_bf16(ah[m], bl[n], acc[m][n], 0, 0, 0);
    }
}

__device__ __forceinline__ void mfma_mainloop(
    const u16* __restrict__ Ah, const u16* __restrict__ Al,
    const u16* __restrict__ Bh, const u16* __restrict__ Bl,
    int K, int rowA0, int rowB0, u16* lds, f32x4 acc[4][4]) {
  const int tid = threadIdx.x;
  const int lane = tid & 63;
  const int w = tid >> 6;
  const int wr = w >> 1, wc = w & 1;

#pragma unroll
  for (int m = 0; m < 4; ++m)
#pragma unroll
    for (int n = 0; n < 4; ++n) acc[m][n] = (f32x4){0.f, 0.f, 0.f, 0.f};

  const int nt = K >> 5;
  stage32(Ah, Al, Bh, Bl, K, rowA0, rowB0, 0, lds, 0, w, lane);
  asm volatile("" ::: "memory");  // keep p0's 8 loads oldest (no interleave)
  stage32(Ah, Al, Bh, Bl, K, rowA0, rowB0, 32, lds, 1, w, lane);

  for (int kt = 0; kt < nt - 1; ++kt) {
    asm volatile("s_waitcnt vmcnt(8)" ::: "memory");  // tile kt landed
    asm volatile("s_barrier" ::: "memory");
    compute32(lds, kt & 1, wr, wc, lane, acc);
    asm volatile("s_barrier" ::: "memory");           // all readers done
    if (kt + 2 < nt)
      stage32(Ah, Al, Bh, Bl, K, rowA0, rowB0, (kt + 2) << 5, lds, kt & 1, w, lane);
  }
  asm volatile("s_waitcnt vmcnt(0)" ::: "memory");    // last tile landed
  asm volatile("s_barrier" ::: "memory");
  compute32(lds, (nt - 1) & 1, wr, wc, lane, acc);
}

// -------- GEMM1: h = silu(x@W1 + b1), write h as bf16 hi/lo ---------------
__global__ __launch_bounds__(256, 2)
void k_gemm1(const u16* __restrict__ xh, const u16* __restrict__ xl,
             const u16* __restrict__ w1h, const u16* __restrict__ w1l,
             const float* __restrict__ b1,
             u16* __restrict__ hh, u16* __restrict__ hl) {
  __shared__ u16 lds[32768];
  const int nbn = C4_ / BN;
  const int bm = blockIdx.x / nbn, bn = blockIdx.x % nbn;
  f32x4 acc[4][4];
  mfma_mainloop(xh, xl, w1h, w1l, D_, bm * BM, bn * BN, lds, acc);
  const int lane = threadIdx.x & 63, w = threadIdx.x >> 6;
  const int wr = w >> 1, wc = w & 1;
#pragma unroll
  for (int m = 0; m < 4; ++m)
#pragma unroll
    for (int n = 0; n < 4; ++n)
#pragma unroll
      for (int j = 0; j < 4; ++j) {
        const int rg = bm * BM + wr * 64 + m * 16 + (lane >> 4) * 4 + j;
        const int cg = bn * BN + wc * 64 + n * 16 + (lane & 15);
        const float v = acc[m][n][j] + b1[cg];
        const float s = v / (1.f + __expf(-v));
        const size_t o = (size_t)rg * C4_ + cg;
        const u16 hi = f2bf(s);
        hh[o] = hi;
        hl[o] = f2bf(s - bf2f(hi));
      }
}

// -------- GEMM2: z = h@W2 + b2, write z f32 + bf16 hi/lo ------------------
__global__ __launch_bounds__(256, 2)
void k_gemm2(const u16* __restrict__ ah, const u16* __restrict__ al,
             const u16* __restrict__ bh, const u16* __restrict__ bl,
             const float* __restrict__ b2,
             float* __restrict__ zf, u16* __restrict__ zh, u16* __restrict__ zl) {
  __shared__ u16 lds[32768];
  const int nbn = C_ / BN;
  const int bm = blockIdx.x / nbn, bn = blockIdx.x % nbn;
  f32x4 acc[4][4];
  mfma_mainloop(ah, al, bh, bl, C4_, bm * BM, bn * BN, lds, acc);
  const int lane = threadIdx.x & 63, w = threadIdx.x >> 6;
  const int wr = w >> 1, wc = w & 1;
#pragma unroll
  for (int m = 0; m < 4; ++m)
#pragma unroll
    for (int n = 0; n < 4; ++n)
#pragma unroll
      for (int j = 0; j < 4; ++j) {
        const int rg = bm * BM + wr * 64 + m * 16 + (lane >> 4) * 4 + j;
        const int cg = bn * BN + wc * 64 + n * 16 + (lane & 15);
        const float v = acc[m][n][j] + b2[cg];
        const size_t o = (size_t)rg * C_ + cg;
        zf[o] = v;
        const u16 hi = f2bf(v);
        zh[o] = hi;
        zl[o] = f2bf(v - bf2f(hi));
      }
}

// -------- GEMM3: s = ||e_k||^2 - 2 z.e_k, fused row-argmin ----------------
__global__ __launch_bounds__(256, 2)
void k_gemm3(const u16* __restrict__ zh, const u16* __restrict__ zl,
             const u16* __restrict__ eh, const u16* __restrict__ el,
             const float* __restrict__ norms, unsigned long long* __restrict__ am) {
  __shared__ u16 lds[32768];
  const int nbn = K_ / BN;
  const int bm = blockIdx.x / nbn, bn = blockIdx.x % nbn;
  f32x4 acc[4][4];
  mfma_mainloop(zh, zl, eh, el, C_, bm * BM, bn * BN, lds, acc);
  const int lane = threadIdx.x & 63, w = threadIdx.x >> 6;
  const int wr = w >> 1, wc = w & 1;
#pragma unroll
  for (int m = 0; m < 4; ++m) {
#pragma unroll
    for (int j = 0; j < 4; ++j) {
      float best = 3.4e38f;
      int bestn = 0x7fffffff;
#pragma unroll
      for (int n = 0; n < 4; ++n) {
        const int cg = bn * BN + wc * 64 + n * 16 + (lane & 15);
        const float s = norms[cg] - 2.f * acc[m][n][j];
        if (s < best) { best = s; bestn = cg; }
      }
      // reduce across the 16 lanes (lane&15) holding this row
#pragma unroll
      for (int off = 1; off <= 8; off <<= 1) {
        const float ob = __shfl_xor(best, off, 64);
        const int obn = __shfl_xor(bestn, off, 64);
        if (ob < best || (ob == best && obn < bestn)) { best = ob; bestn = obn; }
      }
      if ((lane & 15) == 0) {
        const int rg = bm * BM + wr * 64 + m * 16 + (lane >> 4) * 4 + j;
        const unsigned long long key =
            ((unsigned long long)fkey(best) << 32) | (unsigned int)bestn;
        atomicMin(&am[rg], key);
      }
    }
  }
}

// -------- prep kernels ----------------------------------------------------
__global__ void k_split(const float4* __restrict__ in, size_t n4,
                        u16* __restrict__ hi, u16* __restrict__ lo) {
  size_t i = (size_t)blockIdx.x * blockDim.x + threadIdx.x;
  const size_t stride = (size_t)gridDim.x * blockDim.x;
  for (; i < n4; i += stride) {
    const float4 v = in[i];
    const float vv[4] = {v.x, v.y, v.z, v.w};
    u16x4 h, l;
#pragma unroll
    for (int j = 0; j < 4; ++j) {
      const u16 a = f2bf(vv[j]);
      h[j] = a;
      l[j] = f2bf(vv[j] - bf2f(a));
    }
    *(u16x4*)(hi + i * 4) = h;
    *(u16x4*)(lo + i * 4) = l;
  }
}

template <bool WF32>
__global__ void k_tsplit(const float* __restrict__ in, int R, int Cc,
                         u16* __restrict__ hiT, u16* __restrict__ loT,
                         float* __restrict__ f32T) {
  __shared__ float t[32][33];
  const int c0 = blockIdx.x * 32, r0 = blockIdx.y * 32;
  const int tx = threadIdx.x, ty = threadIdx.y;
#pragma unroll
  for (int i = 0; i < 4; ++i)
    t[ty + i * 8][tx] = in[(size_t)(r0 + ty + i * 8) * Cc + (c0 + tx)];
  __syncthreads();
#pragma unroll
  for (int i = 0; i < 4; ++i) {
    const int orow = c0 + ty + i * 8;
    const int ocol = r0 + tx;
    const float v = t[tx][ty + i * 8];
    const size_t o = (size_t)orow * R + ocol;
    const u16 hi = f2bf(v);
    hiT[o] = hi;
    loT[o] = f2bf(v - bf2f(hi));
    if (WF32) f32T[o] = v;
  }
}

__global__ void k_norms(const float* __restrict__ embed, float* __restrict__ norms) {
  const int k = blockIdx.x * blockDim.x + threadIdx.x;
  if (k >= K_) return;
  double s = 0.0;
  for (int c = 0; c < C_; ++c) {
    const float v = embed[(size_t)c * K_ + k];
    s += (double)v * (double)v;
  }
  norms[k] = (float)s;
}

__global__ void k_init(unsigned long long* __restrict__ am, double* __restrict__ dacc) {
  const int i = blockIdx.x * blockDim.x + threadIdx.x;
  if (i < B_) am[i] = 0xFFFFFFFFFFFFFFFFull;
  if (i == 0) *dacc = 0.0;
}

// -------- finalize: gather + LayerNorm + commitment partial ---------------
__global__ __launch_bounds__(256)
void k_finalize(const unsigned long long* __restrict__ am,
                const float* __restrict__ embT, const float* __restrict__ zf,
                const float* __restrict__ gamma, const float* __restrict__ beta,
                float* __restrict__ out, double* __restrict__ dacc) {
  const int row = blockIdx.x;
  const int tid = threadIdx.x;
  const int lane = tid & 63, w = tid >> 6;
  const int idx = (int)(am[row] & 0xFFFFFFFFull);

  const float4 e4 = *(const float4*)(embT + (size_t)idx * C_ + tid * 4);
  float s1 = e4.x + e4.y + e4.z + e4.w;
  float s2 = e4.x * e4.x + e4.y * e4.y + e4.z * e4.z + e4.w * e4.w;
#pragma unroll
  for (int off = 32; off >= 1; off >>= 1) {
    s1 += __shfl_xor(s1, off, 64);
    s2 += __shfl_xor(s2, off, 64);
  }
  __shared__ float r1[4], r2[4], rd[4];
  if (lane == 0) { r1[w] = s1; r2[w] = s2; }
  __syncthreads();
  const float S1 = r1[0] + r1[1] + r1[2] + r1[3];
  const float S2 = r2[0] + r2[1] + r2[2] + r2[3];
  const float mu = S1 * (1.f / C_);
  const float var = S2 * (1.f / C_) - mu * mu;
  const float inv = 1.f / sqrtf(var + 1e-5f);

  const float4 z4 = *(const float4*)(zf + (size_t)row * C_ + tid * 4);
  const float4 g4 = *(const float4*)(gamma + tid * 4);
  const float4 b4 = *(const float4*)(beta + tid * 4);
  float4 o4;
  o4.x = (e4.x - mu) * inv * g4.x + b4.x;
  o4.y = (e4.y - mu) * inv * g4.y + b4.y;
  o4.z = (e4.z - mu) * inv * g4.z + b4.z;
  o4.w = (e4.w - mu) * inv * g4.w + b4.w;
  *(float4*)(out + (size_t)row * C_ + tid * 4) = o4;

  const float dx = e4.x - z4.x, dy = e4.y - z4.y, dz = e4.z - z4.z, dw = e4.w - z4.w;
  float d = dx * dx + dy * dy + dz * dz + dw * dw;
#pragma unroll
  for (int off = 32; off >= 1; off >>= 1) d += __shfl_xor(d, off, 64);
  __syncthreads();
  if (lane == 0) rd[w] = d;
  __syncthreads();
  if (tid == 0) atomicAdd(dacc, (double)(rd[0] + rd[1] + rd[2] + rd[3]));
}

__global__ void k_wdiff(const double* __restrict__ dacc, float* __restrict__ out) {
  out[(size_t)B_ * C_] = (float)(0.01 * (*dacc) / ((double)B_ * (double)C_));
}

// ---------------------------------------------------------------------------
extern "C" void kernel_launch(void* const* d_in, const int* in_sizes, int n_in,
                              void* d_out, int out_size, void* d_ws, size_t ws_size,
                              hipStream_t stream) {
  const float* x     = (const float*)d_in[0];
  const float* W1    = (const float*)d_in[1];
  const float* b1    = (const float*)d_in[2];
  const float* W2    = (const float*)d_in[3];
  const float* b2    = (const float*)d_in[4];
  const float* gamma = (const float*)d_in[5];
  const float* beta  = (const float*)d_in[6];
  const float* embed = (const float*)d_in[7];
  float* out = (float*)d_out;

  char* ws = (char*)d_ws;
  const size_t MB64 = 67108864ull;  // 8192*4096*2
  u16* xh  = (u16*)(ws);
  u16* xl  = (u16*)(ws + MB64);
  u16* w1h = (u16*)(ws + 2 * MB64);
  u16* w1l = (u16*)(ws + 2 * MB64 + 33554432ull);
  u16* hh  = (u16*)(ws + 3 * MB64);
  u16* hl  = (u16*)(ws + 4 * MB64);
  u16* w2h = (u16*)(ws);
  u16* w2l = (u16*)(ws + 8388608ull);
  float* zf = (float*)(ws + 16777216ull);
  u16* zh  = (u16*)(ws + MB64);
  u16* zl  = (u16*)(ws + MB64 + 16777216ull);
  float* norms = (float*)(ws + MB64 + 33554432ull);
  unsigned long long* am = (unsigned long long*)(ws + MB64 + 33554432ull + 65536ull);
  double* dacc = (double*)(ws + MB64 + 33554432ull + 131072ull);
  float* embT = (float*)(ws + 2 * MB64);
  u16* eh  = (u16*)(ws + 2 * MB64 + 33554432ull);
  u16* el  = (u16*)(ws + 2 * MB64 + 50331648ull);

  // 1. split x -> xh/xl
  k_split<<<2048, 256, 0, stream>>>((const float4*)x, (size_t)B_ * D_ / 4, xh, xl);
  // 2. W1 [D][4C] -> W1T hi/lo [4C][D]
  k_tsplit<false><<<dim3(C4_ / 32, D_ / 32), dim3(32, 8), 0, stream>>>(W1, D_, C4_, w1h, w1l, nullptr);
  // 3. GEMM1 (+bias+SiLU+split)
  k_gemm1<<<(B_ / BM) * (C4_ / BN), 256, 0, stream>>>(xh, xl, w1h, w1l, b1, hh, hl);
  // 4. W2 [4C][C] -> W2T hi/lo [C][4C]  (region A is free now)
  k_tsplit<false><<<dim3(C_ / 32, C4_ / 32), dim3(32, 8), 0, stream>>>(W2, C4_, C_, w2h, w2l, nullptr);
  // 5. GEMM2 (+bias, write z f32 + hi/lo)
  k_gemm2<<<(B_ / BM) * (C_ / BN), 256, 0, stream>>>(hh, hl, w2h, w2l, b2, zf, zh, zl);
  // 6. embed [C][K] -> embT f32 + hi/lo [K][C]  (regions C/D free now)
  k_tsplit<true><<<dim3(K_ / 32, C_ / 32), dim3(32, 8), 0, stream>>>(embed, C_, K_, eh, el, embT);
  // 7. codebook column norms (f64 accumulate)
  k_norms<<<K_ / 256, 256, 0, stream>>>(embed, norms);
  // 8. init argmin keys + diff accumulator
  k_init<<<B_ / 256, 256, 0, stream>>>(am, dacc);
  // 9. GEMM3 + fused argmin
  k_gemm3<<<(B_ / BM) * (K_ / BN), 256, 0, stream>>>(zh, zl, eh, el, norms, am);
  // 10. gather + LayerNorm + commitment partial sums
  k_finalize<<<B_, 256, 0, stream>>>(am, embT, zf, gamma, beta, out, dacc);
  // 11. scalar diff output
  k_wdiff<<<1, 1, 0, stream>>>(dacc, out);
}

// Round 5
// 1385.098 us; speedup vs baseline: 1.3627x; 1.1552x over previous
//
#include <hip/hip_runtime.h>
#include <stdint.h>

typedef unsigned short u16;
typedef __attribute__((ext_vector_type(4))) float f32x4;
typedef __attribute__((ext_vector_type(8))) __bf16 bf16x8;
typedef __attribute__((ext_vector_type(4))) u16 u16x4;

#define B_  8192
#define D_  4096
#define C4_ 4096
#define C_  1024
#define K_  8192
#define BM  128
#define BN  128
#define CAP 64

__device__ __forceinline__ void load_lds16(const void* g, void* l) {
  __builtin_amdgcn_global_load_lds(
      (const __attribute__((address_space(1))) unsigned int*)g,
      (__attribute__((address_space(3))) unsigned int*)l, 16, 0, 0);
}

__device__ __forceinline__ u16 f2bf(float v) {
  unsigned int u = __float_as_uint(v);
  return (u16)((u + 0x7FFFu + ((u >> 16) & 1u)) >> 16);   // RNE
}
__device__ __forceinline__ float bf2f(u16 u) {
  return __uint_as_float(((unsigned int)u) << 16);
}
__device__ __forceinline__ u16 f2h(float v) {
  _Float16 h = (_Float16)v; u16 b; __builtin_memcpy(&b, &h, 2); return b;
}
__device__ __forceinline__ float h2f(u16 b) {
  _Float16 h; __builtin_memcpy(&h, &b, 2); return (float)h;
}

// ---------------- split-bf16 GEMM mainloop (R2-verified: T2 swizzle, ------
// single-buffer BK=64, 2 blocks/CU). A: [M][K] hi/lo bf16 (K contig).
// B: [N][K] hi/lo bf16 (B^T). 128x128 tile, 4 waves, 4x4 16x16 frags/wave.
// acc = Ah*Bh + Al*Bh + Ah*Bl  (~17-bit effective input mantissa).
// Rows are 128 B = 8 x 16B slots; LDS[row][s] holds global slot s^(row&7)
// (pre-swizzled global source + swizzled ds_read; verified 0 conflicts).
__device__ __forceinline__ void mfma_mainloop(
    const u16* __restrict__ Ah, const u16* __restrict__ Al,
    const u16* __restrict__ Bh, const u16* __restrict__ Bl,
    int K, int rowA0, int rowB0, u16* lds, f32x4 acc[4][4]) {
  const int tid = threadIdx.x;
  const int lane = tid & 63;
  const int w = tid >> 6;
  const int wr = w >> 1, wc = w & 1;

  u16* As_h = lds;            // [128][64]
  u16* As_l = lds + 8192;
  u16* Bs_h = lds + 16384;
  u16* Bs_l = lds + 24576;

#pragma unroll
  for (int m = 0; m < 4; ++m)
#pragma unroll
    for (int n = 0; n < 4; ++n) acc[m][n] = (f32x4){0.f, 0.f, 0.f, 0.f};

  const int rstage = w * 8 + (lane >> 3);
  const int estage = (((lane & 7) ^ (lane >> 3)) << 3);

  for (int k0 = 0; k0 < K; k0 += 64) {
#pragma unroll
    for (int c = 0; c < 4; ++c) {
      const int r = c * 32 + rstage;
      const size_t ga = (size_t)(rowA0 + r) * K + (k0 + estage);
      const size_t gb = (size_t)(rowB0 + r) * K + (k0 + estage);
      const int lo = (c * 32 + w * 8) * 64;
      load_lds16(Ah + ga, As_h + lo);
      load_lds16(Al + ga, As_l + lo);
      load_lds16(Bh + gb, Bs_h + lo);
      load_lds16(Bl + gb, Bs_l + lo);
    }
    __syncthreads();
#pragma unroll
    for (int ks = 0; ks < 2; ++ks) {
      bf16x8 ah[4], al[4], bh[4], bl[4];
      const int kof = (((ks * 4 + (lane >> 4)) ^ (lane & 7)) << 3);
#pragma unroll
      for (int m = 0; m < 4; ++m) {
        const int ra = (wr * 64 + m * 16 + (lane & 15)) * 64 + kof;
        ah[m] = *(const bf16x8*)(As_h + ra);
        al[m] = *(const bf16x8*)(As_l + ra);
      }
#pragma unroll
      for (int n = 0; n < 4; ++n) {
        const int rb = (wc * 64 + n * 16 + (lane & 15)) * 64 + kof;
        bh[n] = *(const bf16x8*)(Bs_h + rb);
        bl[n] = *(const bf16x8*)(Bs_l + rb);
      }
#pragma unroll
      for (int m = 0; m < 4; ++m)
#pragma unroll
        for (int n = 0; n < 4; ++n) {
          acc[m][n] = __builtin_amdgcn_mfma_f32_16x16x32_bf16(ah[m], bh[n], acc[m][n], 0, 0, 0);
          acc[m][n] = __builtin_amdgcn_mfma_f32_16x16x32_bf16(al[m], bh[n], acc[m][n], 0, 0, 0);
          acc[m][n] = __builtin_amdgcn_mfma_f32_16x16x32_bf16(ah[m], bl[n], acc[m][n], 0, 0, 0);
        }
    }
    __syncthreads();
  }
}

// -------- GEMM1: h = silu(x@W1 + b1), write h as bf16 hi/lo ---------------
__global__ __launch_bounds__(256, 2)
void k_gemm1(const u16* __restrict__ xh, const u16* __restrict__ xl,
             const u16* __restrict__ w1h, const u16* __restrict__ w1l,
             const float* __restrict__ b1,
             u16* __restrict__ hh, u16* __restrict__ hl) {
  __shared__ u16 lds[32768];
  const int nbn = C4_ / BN;
  const int bm = blockIdx.x / nbn, bn = blockIdx.x % nbn;
  f32x4 acc[4][4];
  mfma_mainloop(xh, xl, w1h, w1l, D_, bm * BM, bn * BN, lds, acc);
  const int lane = threadIdx.x & 63, w = threadIdx.x >> 6;
  const int wr = w >> 1, wc = w & 1;
#pragma unroll
  for (int m = 0; m < 4; ++m)
#pragma unroll
    for (int n = 0; n < 4; ++n)
#pragma unroll
      for (int j = 0; j < 4; ++j) {
        const int rg = bm * BM + wr * 64 + m * 16 + (lane >> 4) * 4 + j;
        const int cg = bn * BN + wc * 64 + n * 16 + (lane & 15);
        const float v = acc[m][n][j] + b1[cg];
        const float s = v / (1.f + __expf(-v));
        const size_t o = (size_t)rg * C4_ + cg;
        const u16 hi = f2bf(s);
        hh[o] = hi;
        hl[o] = f2bf(s - bf2f(hi));
      }
}

// -------- GEMM2: z = h@W2 + b2, write z f32 + bf16 hi ---------------------
__global__ __launch_bounds__(256, 2)
void k_gemm2(const u16* __restrict__ ah, const u16* __restrict__ al,
             const u16* __restrict__ bh, const u16* __restrict__ bl,
             const float* __restrict__ b2,
             float* __restrict__ zf, u16* __restrict__ zh) {
  __shared__ u16 lds[32768];
  const int nbn = C_ / BN;
  const int bm = blockIdx.x / nbn, bn = blockIdx.x % nbn;
  f32x4 acc[4][4];
  mfma_mainloop(ah, al, bh, bl, C4_, bm * BM, bn * BN, lds, acc);
  const int lane = threadIdx.x & 63, w = threadIdx.x >> 6;
  const int wr = w >> 1, wc = w & 1;
#pragma unroll
  for (int m = 0; m < 4; ++m)
#pragma unroll
    for (int n = 0; n < 4; ++n)
#pragma unroll
      for (int j = 0; j < 4; ++j) {
        const int rg = bm * BM + wr * 64 + m * 16 + (lane >> 4) * 4 + j;
        const int cg = bn * BN + wc * 64 + n * 16 + (lane & 15);
        const float v = acc[m][n][j] + b2[cg];
        const size_t o = (size_t)rg * C_ + cg;
        zf[o] = v;
        zh[o] = f2bf(v);
      }
}

// -------- GEMM3 cheap pass: p = z.e (plain bf16, 1 product) --------------
// Writes dotm[r][k] = f16(p). Candidate selection + exact rescore happen in
// k_scan / k_rescore with a rigorous error bound (see k_scan).
__global__ __launch_bounds__(256, 2)
void k_gemm3c(const u16* __restrict__ zh, const u16* __restrict__ eh,
              u16* __restrict__ dotm) {
  __shared__ u16 lds[16384];   // As_h [128][64] + Bs_h [128][64] = 32 KB
  const int nbn = K_ / BN;
  const int bm = blockIdx.x / nbn, bn = blockIdx.x % nbn;
  const int tid = threadIdx.x, lane = tid & 63, w = tid >> 6;
  const int wr = w >> 1, wc = w & 1;
  f32x4 acc[4][4];
#pragma unroll
  for (int m = 0; m < 4; ++m)
#pragma unroll
    for (int n = 0; n < 4; ++n) acc[m][n] = (f32x4){0.f, 0.f, 0.f, 0.f};

  const int rstage = w * 8 + (lane >> 3);
  const int estage = (((lane & 7) ^ (lane >> 3)) << 3);
  for (int k0 = 0; k0 < C_; k0 += 64) {
#pragma unroll
    for (int c = 0; c < 4; ++c) {
      const int r = c * 32 + rstage;
      const size_t ga = (size_t)(bm * BM + r) * C_ + (k0 + estage);
      const size_t gb = (size_t)(bn * BN + r) * C_ + (k0 + estage);
      const int lo = (c * 32 + w * 8) * 64;
      load_lds16(zh + ga, lds + lo);
      load_lds16(eh + gb, lds + 8192 + lo);
    }
    __syncthreads();
#pragma unroll
    for (int ks = 0; ks < 2; ++ks) {
      bf16x8 ah[4], bh[4];
      const int kof = (((ks * 4 + (lane >> 4)) ^ (lane & 7)) << 3);
#pragma unroll
      for (int m = 0; m < 4; ++m)
        ah[m] = *(const bf16x8*)(lds + (wr * 64 + m * 16 + (lane & 15)) * 64 + kof);
#pragma unroll
      for (int n = 0; n < 4; ++n)
        bh[n] = *(const bf16x8*)(lds + 8192 + (wc * 64 + n * 16 + (lane & 15)) * 64 + kof);
#pragma unroll
      for (int m = 0; m < 4; ++m)
#pragma unroll
        for (int n = 0; n < 4; ++n)
          acc[m][n] = __builtin_amdgcn_mfma_f32_16x16x32_bf16(ah[m], bh[n], acc[m][n], 0, 0, 0);
    }
    __syncthreads();
  }
  // repack through LDS (mainloop done; buffer reusable) for coalesced stores
  u16* outp = lds;  // [128][128] f16 = 32 KB
#pragma unroll
  for (int m = 0; m < 4; ++m)
#pragma unroll
    for (int n = 0; n < 4; ++n)
#pragma unroll
      for (int j = 0; j < 4; ++j) {
        const int rl = wr * 64 + m * 16 + (lane >> 4) * 4 + j;
        const int cl = wc * 64 + n * 16 + (lane & 15);
        outp[rl * 128 + cl] = f2h(acc[m][n][j]);
      }
  __syncthreads();
  const size_t base = (size_t)(bm * BM) * K_ + bn * BN;
  for (int i = tid; i < 128 * 64; i += 256) {   // 4B units: 128 rows x 64
    const int r = i >> 6, c = (i & 63) * 2;
    *(unsigned int*)(dotm + base + (size_t)r * K_ + c) =
        *(const unsigned int*)(outp + r * 128 + c);
  }
}

// -------- scan: per-row min + candidates within rigorous bound ------------
// sc_k = norms_k - 2*h2f(dotm[r][k]).  |sc_k - true_k| <= B where
// B = 0.010*||z||*||e||max + 0.01  (bf16 2^-8*1.002 + f16 store 2^-11*2 +
// f32 accum 6e-5, each times ||z||*||e||, + norm rounding slack).
// Candidate set {k: sc_k <= min_sc + 2B} provably contains the true argmin.
__global__ __launch_bounds__(256)
void k_scan(const u16* __restrict__ dotm, const float* __restrict__ norms,
            const float* __restrict__ zn2, const unsigned int* __restrict__ emaxb,
            int* __restrict__ cand, int* __restrict__ candcnt) {
  __shared__ __align__(16) u16 srow[K_];
  __shared__ float rmin[4];
  __shared__ int lcnt;
  const int r = blockIdx.x, tid = threadIdx.x;
  const size_t base = (size_t)r * K_;
  for (int i = tid; i < K_ / 8; i += 256)
    ((uint4*)srow)[i] = ((const uint4*)(dotm + base))[i];
  if (tid == 0) lcnt = 0;
  __syncthreads();
  float mymin = 3.4e38f;
  for (int k = tid; k < K_; k += 256)
    mymin = fminf(mymin, norms[k] - 2.f * h2f(srow[k]));
#pragma unroll
  for (int off = 32; off >= 1; off >>= 1)
    mymin = fminf(mymin, __shfl_xor(mymin, off, 64));
  if ((tid & 63) == 0) rmin[tid >> 6] = mymin;
  __syncthreads();
  const float gmin = fminf(fminf(rmin[0], rmin[1]), fminf(rmin[2], rmin[3]));
  const float bnd = 0.010f * sqrtf(zn2[r]) * sqrtf(__uint_as_float(*emaxb)) + 0.01f;
  const float win = gmin + 2.f * bnd;
  for (int k = tid; k < K_; k += 256) {
    const float sc = norms[k] - 2.f * h2f(srow[k]);
    if (sc <= win) {
      const int p = atomicAdd(&lcnt, 1);
      if (p < CAP) cand[r * CAP + p] = k;
    }
  }
  __syncthreads();
  if (tid == 0) candcnt[r] = lcnt;
}

// -------- rescore: exact f64 distance over candidates ---------------------
__global__ __launch_bounds__(64)
void k_rescore(const int* __restrict__ cand, const int* __restrict__ candcnt,
               const float* __restrict__ zf, const float* __restrict__ embT,
               int* __restrict__ idx) {
  const int r = blockIdx.x, lane = threadIdx.x;
  const int cnt = candcnt[r];
  if (cnt <= 1) { if (lane == 0) idx[r] = cand[r * CAP]; return; }
  const bool full = cnt > CAP;           // never expected; rigorous fallback
  const int n = full ? K_ : cnt;
  double bestd = 1e300; int bestk = 0x7fffffff;
  for (int c = 0; c < n; ++c) {
    const int k = full ? c : cand[r * CAP + c];
    double s = 0.0;
    for (int i = lane; i < C_; i += 64) {
      const double d = (double)zf[(size_t)r * C_ + i] - (double)embT[(size_t)k * C_ + i];
      s += d * d;
    }
#pragma unroll
    for (int off = 32; off >= 1; off >>= 1) s += __shfl_xor(s, off, 64);
    if (s < bestd || (s == bestd && k < bestk)) { bestd = s; bestk = k; }
  }
  if (lane == 0) idx[r] = bestk;
}

// -------- prep kernels ----------------------------------------------------
__global__ void k_split(const float4* __restrict__ in, size_t n4,
                        u16* __restrict__ hi, u16* __restrict__ lo) {
  size_t i = (size_t)blockIdx.x * blockDim.x + threadIdx.x;
  const size_t stride = (size_t)gridDim.x * blockDim.x;
  for (; i < n4; i += stride) {
    const float4 v = in[i];
    const float vv[4] = {v.x, v.y, v.z, v.w};
    u16x4 h, l;
#pragma unroll
    for (int j = 0; j < 4; ++j) {
      const u16 a = f2bf(vv[j]);
      h[j] = a;
      l[j] = f2bf(vv[j] - bf2f(a));
    }
    *(u16x4*)(hi + i * 4) = h;
    *(u16x4*)(lo + i * 4) = l;
  }
}

template <bool WF32, bool WLO>
__global__ void k_tsplit(const float* __restrict__ in, int R, int Cc,
                         u16* __restrict__ hiT, u16* __restrict__ loT,
                         float* __restrict__ f32T) {
  __shared__ float t[32][33];
  const int c0 = blockIdx.x * 32, r0 = blockIdx.y * 32;
  const int tx = threadIdx.x, ty = threadIdx.y;
#pragma unroll
  for (int i = 0; i < 4; ++i)
    t[ty + i * 8][tx] = in[(size_t)(r0 + ty + i * 8) * Cc + (c0 + tx)];
  __syncthreads();
#pragma unroll
  for (int i = 0; i < 4; ++i) {
    const int orow = c0 + ty + i * 8;
    const int ocol = r0 + tx;
    const float v = t[tx][ty + i * 8];
    const size_t o = (size_t)orow * R + ocol;
    const u16 hi = f2bf(v);
    hiT[o] = hi;
    if (WLO) loT[o] = f2bf(v - bf2f(hi));
    if (WF32) f32T[o] = v;
  }
}

// row-wise squared L2 norm of [N][1024] f32, f64 accumulation
__global__ __launch_bounds__(256)
void k_rownorm(const float* __restrict__ in, float* __restrict__ out,
               unsigned int* __restrict__ maxb, int domax) {
  const int r = blockIdx.x, tid = threadIdx.x;
  const float4 v = *(const float4*)(in + (size_t)r * 1024 + tid * 4);
  double s = (double)v.x * v.x + (double)v.y * v.y +
             (double)v.z * v.z + (double)v.w * v.w;
#pragma unroll
  for (int off = 32; off >= 1; off >>= 1) s += __shfl_xor(s, off, 64);
  __shared__ double sw[4];
  if ((tid & 63) == 0) sw[tid >> 6] = s;
  __syncthreads();
  if (tid == 0) {
    const float t = (float)(sw[0] + sw[1] + sw[2] + sw[3]);
    out[r] = t;
    if (domax) atomicMax(maxb, __float_as_uint(t));
  }
}

__global__ void k_init(double* __restrict__ dacc, unsigned int* __restrict__ emaxb) {
  *dacc = 0.0;
  *emaxb = 0u;
}

// -------- finalize: gather + LayerNorm + commitment partial ---------------
__global__ __launch_bounds__(256)
void k_finalize(const int* __restrict__ idx,
                const float* __restrict__ embT, const float* __restrict__ zf,
                const float* __restrict__ gamma, const float* __restrict__ beta,
                float* __restrict__ out, double* __restrict__ dacc) {
  const int row = blockIdx.x;
  const int tid = threadIdx.x;
  const int lane = tid & 63, w = tid >> 6;
  const int id = idx[row];

  const float4 e4 = *(const float4*)(embT + (size_t)id * C_ + tid * 4);
  float s1 = e4.x + e4.y + e4.z + e4.w;
  float s2 = e4.x * e4.x + e4.y * e4.y + e4.z * e4.z + e4.w * e4.w;
#pragma unroll
  for (int off = 32; off >= 1; off >>= 1) {
    s1 += __shfl_xor(s1, off, 64);
    s2 += __shfl_xor(s2, off, 64);
  }
  __shared__ float r1[4], r2[4], rd[4];
  if (lane == 0) { r1[w] = s1; r2[w] = s2; }
  __syncthreads();
  const float S1 = r1[0] + r1[1] + r1[2] + r1[3];
  const float S2 = r2[0] + r2[1] + r2[2] + r2[3];
  const float mu = S1 * (1.f / C_);
  const float var = S2 * (1.f / C_) - mu * mu;
  const float inv = 1.f / sqrtf(var + 1e-5f);

  const float4 z4 = *(const float4*)(zf + (size_t)row * C_ + tid * 4);
  const float4 g4 = *(const float4*)(gamma + tid * 4);
  const float4 b4 = *(const float4*)(beta + tid * 4);
  float4 o4;
  o4.x = (e4.x - mu) * inv * g4.x + b4.x;
  o4.y = (e4.y - mu) * inv * g4.y + b4.y;
  o4.z = (e4.z - mu) * inv * g4.z + b4.z;
  o4.w = (e4.w - mu) * inv * g4.w + b4.w;
  *(float4*)(out + (size_t)row * C_ + tid * 4) = o4;

  const float dx = e4.x - z4.x, dy = e4.y - z4.y, dz = e4.z - z4.z, dw = e4.w - z4.w;
  float d = dx * dx + dy * dy + dz * dz + dw * dw;
#pragma unroll
  for (int off = 32; off >= 1; off >>= 1) d += __shfl_xor(d, off, 64);
  __syncthreads();
  if (lane == 0) rd[w] = d;
  __syncthreads();
  if (tid == 0) atomicAdd(dacc, (double)(rd[0] + rd[1] + rd[2] + rd[3]));
}

__global__ void k_wdiff(const double* __restrict__ dacc, float* __restrict__ out) {
  out[(size_t)B_ * C_] = (float)(0.01 * (*dacc) / ((double)B_ * (double)C_));
}

// ---------------------------------------------------------------------------
extern "C" void kernel_launch(void* const* d_in, const int* in_sizes, int n_in,
                              void* d_out, int out_size, void* d_ws, size_t ws_size,
                              hipStream_t stream) {
  const float* x     = (const float*)d_in[0];
  const float* W1    = (const float*)d_in[1];
  const float* b1    = (const float*)d_in[2];
  const float* W2    = (const float*)d_in[3];
  const float* b2    = (const float*)d_in[4];
  const float* gamma = (const float*)d_in[5];
  const float* beta  = (const float*)d_in[6];
  const float* embed = (const float*)d_in[7];
  float* out = (float*)d_out;

  char* ws = (char*)d_ws;
  const size_t M = 1048576ull;
  // phase 1 (gemm1): xh 0..64M, xl 64..128M, w1h 128..160M, w1l 160..192M,
  //                  hh 192..256M, hl 256..320M
  // phase 2+ (reusing dead regions):
  //   w2h 0..8M, w2l 8..16M, zf 16..48M, zh 48..64M        (over xh)
  //   embT 64..96M, eh 96..112M                            (over xl)
  //   norms/zn2/candcnt/idx/emaxb/dacc/cand @ 112..115M    (over xl)
  //   dotm 192..320M (128 MB f16)                          (over hh/hl)
  u16* xh  = (u16*)(ws);
  u16* xl  = (u16*)(ws + 64 * M);
  u16* w1h = (u16*)(ws + 128 * M);
  u16* w1l = (u16*)(ws + 160 * M);
  u16* hh  = (u16*)(ws + 192 * M);
  u16* hl  = (u16*)(ws + 256 * M);
  u16* w2h = (u16*)(ws);
  u16* w2l = (u16*)(ws + 8 * M);
  float* zf = (float*)(ws + 16 * M);
  u16* zh  = (u16*)(ws + 48 * M);
  float* embT = (float*)(ws + 64 * M);
  u16* eh  = (u16*)(ws + 96 * M);
  float* norms = (float*)(ws + 112 * M);
  float* zn2   = (float*)(ws + 112 * M + 65536ull);
  int* candcnt = (int*)(ws + 112 * M + 131072ull);
  int* idx     = (int*)(ws + 112 * M + 196608ull);
  unsigned int* emaxb = (unsigned int*)(ws + 112 * M + 262144ull);
  double* dacc = (double*)(ws + 112 * M + 262144ull + 64ull);
  int* cand    = (int*)(ws + 113 * M);
  u16* dotm    = (u16*)(ws + 192 * M);

  // 1. split x -> xh/xl
  k_split<<<2048, 256, 0, stream>>>((const float4*)x, (size_t)B_ * D_ / 4, xh, xl);
  // 2. W1 [D][4C] -> W1T hi/lo [4C][D]
  k_tsplit<false, true><<<dim3(C4_ / 32, D_ / 32), dim3(32, 8), 0, stream>>>(W1, D_, C4_, w1h, w1l, nullptr);
  // 3. GEMM1 (+bias+SiLU+split)
  k_gemm1<<<(B_ / BM) * (C4_ / BN), 256, 0, stream>>>(xh, xl, w1h, w1l, b1, hh, hl);
  // 4. W2 [4C][C] -> W2T hi/lo [C][4C]
  k_tsplit<false, true><<<dim3(C_ / 32, C4_ / 32), dim3(32, 8), 0, stream>>>(W2, C4_, C_, w2h, w2l, nullptr);
  // 5. GEMM2 (+bias, write z f32 + bf16 hi)
  k_gemm2<<<(B_ / BM) * (C_ / BN), 256, 0, stream>>>(hh, hl, w2h, w2l, b2, zf, zh);
  // 6. embed [C][K] -> embT f32 + bf16 hi [K][C]
  k_tsplit<true, false><<<dim3(K_ / 32, C_ / 32), dim3(32, 8), 0, stream>>>(embed, C_, K_, eh, nullptr, embT);
  // 7. init accumulators (before norm max)
  k_init<<<1, 1, 0, stream>>>(dacc, emaxb);
  // 8. codebook norms (coalesced from embT, f64) + max; z row norms
  k_rownorm<<<K_, 256, 0, stream>>>(embT, norms, emaxb, 1);
  k_rownorm<<<B_, 256, 0, stream>>>(zf, zn2, emaxb, 0);
  // 9. cheap 1-product dot matrix
  k_gemm3c<<<(B_ / BM) * (K_ / BN), 256, 0, stream>>>(zh, eh, dotm);
  // 10. per-row min + candidate window
  k_scan<<<B_, 256, 0, stream>>>(dotm, norms, zn2, emaxb, cand, candcnt);
  // 11. exact f64 rescore -> final indices
  k_rescore<<<B_, 64, 0, stream>>>(cand, candcnt, zf, embT, idx);
  // 12. gather + LayerNorm + commitment partial sums
  k_finalize<<<B_, 256, 0, stream>>>(idx, embT, zf, gamma, beta, out, dacc);
  // 13. scalar diff output
  k_wdiff<<<1, 1, 0, stream>>>(dacc, out);
}

// Round 6
// 1276.006 us; speedup vs baseline: 1.4792x; 1.0855x over previous
//
#include <hip/hip_runtime.h>
#include <stdint.h>

typedef unsigned short u16;
typedef __attribute__((ext_vector_type(4))) float f32x4;
typedef __attribute__((ext_vector_type(8))) __bf16 bf16x8;
typedef __attribute__((ext_vector_type(4))) u16 u16x4;

#define B_  8192
#define D_  4096
#define C4_ 4096
#define C_  1024
#define K_  8192
#define BM  128
#define BN  128
#define CAP 64

__device__ __forceinline__ void load_lds16(const void* g, void* l) {
  __builtin_amdgcn_global_load_lds(
      (const __attribute__((address_space(1))) unsigned int*)g,
      (__attribute__((address_space(3))) unsigned int*)l, 16, 0, 0);
}

__device__ __forceinline__ u16 f2bf(float v) {
  unsigned int u = __float_as_uint(v);
  return (u16)((u + 0x7FFFu + ((u >> 16) & 1u)) >> 16);   // RNE
}
__device__ __forceinline__ float bf2f(u16 u) {
  return __uint_as_float(((unsigned int)u) << 16);
}
__device__ __forceinline__ u16 f2h(float v) {
  _Float16 h = (_Float16)v; u16 b; __builtin_memcpy(&b, &h, 2); return b;
}
__device__ __forceinline__ float h2f(u16 b) {
  _Float16 h; __builtin_memcpy(&h, &b, 2); return (float)h;
}

// ===================== GEMM1: 256x256 tile, 8-phase counted-vmcnt =========
// 512 thr (8 waves: wr=w>>2, wc=w&3), BK=32, 2 K-tiles/iter, 3-product
// split-bf16 (acc = Ah*Bh + Al*Bh + Ah*Bl). LDS 128 KB:
//   buf P at P*32768 u16: As_h[256][32] | As_l | Bs_h | Bs_l (8192 u16 each)
// Rows = 64 B = 4 x 16B slots; swizzle slot ^= (row>>1)&3 on BOTH the
// pre-swizzled global source and the ds_read (R4's row&3 gave 4-way
// conflicts; (row>>1)&3 spreads 16 rows over all 8 bank-phases 2-way).
// Per iter: 8 phases, 2 stage-loads each; waits [3,4,5,6,3,4,5,6] (never 0)
// give each chunk 2-4 phases of flight. Final iter peeled: [3,4,5,6,3,2,1,0].
// Single asm s_barrier per phase: every stage targets a region whose last
// ds_readers retired >=4 barriers earlier (R4-proven mechanics).

#define VMW(N) asm volatile("s_waitcnt vmcnt(" #N ")" ::: "memory")
#define BARR() asm volatile("s_barrier" ::: "memory")

// stage Bh or Bl of buffer P (2 loads: rows 0-127, 128-255)
#define STAGE_BX(P, GPTR, LOFF, k0)                                          \
  { load_lds16((GPTR) + sB_base + (size_t)(k0),                              \
               lds + (P) * 32768 + (LOFF) + w * 512);                        \
    load_lds16((GPTR) + sB_base + (size_t)128 * Ksz + (size_t)(k0),          \
               lds + (P) * 32768 + (LOFF) + 4096 + w * 512); }

// stage A-chunk j (rows {j*32..+31} of both wr-halves, Ah by waves 0-3,
// Al by waves 4-7; 1 load)
#define STAGE_A1(P, j, k0)                                                   \
  { load_lds16(Asrc + sA_base + (size_t)((j) * 32) * Ksz + (size_t)(k0),     \
               lds + (P) * 32768 + aldsb + (j) * 1024); }

#define LOAD_B(P)                                                            \
  { const u16* bb = lds + (P) * 32768;                                       \
    _Pragma("unroll") for (int n = 0; n < 4; ++n) {                          \
      bhf[n] = *(const bf16x8*)(bb + ardB + n * 512);                        \
      blf[n] = *(const bf16x8*)(bb + 8192 + ardB + n * 512); } }

#define PH_A(P, Q, ...)                                                      \
  { const u16* bb = lds + (P) * 32768;                                       \
    const bf16x8 a0h = *(const bf16x8*)(bb + ardA + ((Q)*2 + 0) * 512);      \
    const bf16x8 a0l = *(const bf16x8*)(bb + 8192 + ardA + ((Q)*2+0) * 512); \
    const bf16x8 a1h = *(const bf16x8*)(bb + ardA + ((Q)*2 + 1) * 512);      \
    const bf16x8 a1l = *(const bf16x8*)(bb + 8192 + ardA + ((Q)*2+1) * 512); \
    __VA_ARGS__                                                              \
    __builtin_amdgcn_s_setprio(1);                                           \
    _Pragma("unroll") for (int n = 0; n < 4; ++n) {                          \
      acc[(Q)*2+0][n] = __builtin_amdgcn_mfma_f32_16x16x32_bf16(a0h, bhf[n], acc[(Q)*2+0][n], 0,0,0); \
      acc[(Q)*2+0][n] = __builtin_amdgcn_mfma_f32_16x16x32_bf16(a0l, bhf[n], acc[(Q)*2+0][n], 0,0,0); \
      acc[(Q)*2+0][n] = __builtin_amdgcn_mfma_f32_16x16x32_bf16(a0h, blf[n], acc[(Q)*2+0][n], 0,0,0); \
      acc[(Q)*2+1][n] = __builtin_amdgcn_mfma_f32_16x16x32_bf16(a1h, bhf[n], acc[(Q)*2+1][n], 0,0,0); \
      acc[(Q)*2+1][n] = __builtin_amdgcn_mfma_f32_16x16x32_bf16(a1l, bhf[n], acc[(Q)*2+1][n], 0,0,0); \
      acc[(Q)*2+1][n] = __builtin_amdgcn_mfma_f32_16x16x32_bf16(a1h, blf[n], acc[(Q)*2+1][n], 0,0,0); \
    }                                                                        \
    __builtin_amdgcn_s_setprio(0); }

__global__ __launch_bounds__(512, 2)
void k_gemm1(const u16* __restrict__ xh, const u16* __restrict__ xl,
             const u16* __restrict__ w1h, const u16* __restrict__ w1l,
             const float* __restrict__ b1,
             u16* __restrict__ hh, u16* __restrict__ hl) {
  extern __shared__ u16 lds[];
  const int tid = threadIdx.x;
  const int lane = tid & 63;
  const int w = tid >> 6;
  const int wr = w >> 2, wc = w & 3;
  const int rlow = lane & 15;
  const size_t Ksz = D_;
  const int nbn = C4_ / 256;
  const int bm = blockIdx.x / nbn, bn = blockIdx.x % nbn;
  const int rowA0 = bm * 256, rowB0 = bn * 256;
  const u16* __restrict__ Bhg = w1h;
  const u16* __restrict__ Blg = w1l;
  const u16* __restrict__ Asrc = (w < 4) ? xh : xl;

  // staging address precompute (pre-swizzled global slot)
  const int gslot8 = (((lane & 3) ^ ((lane >> 3) & 3)) << 3);
  const size_t sB_base = (size_t)(rowB0 + w * 16 + (lane >> 2)) * Ksz + gslot8;
  const size_t sA_base =
      (size_t)(rowA0 + ((w >> 1) & 1) * 128 + (w & 1) * 16 + (lane >> 2)) * Ksz + gslot8;
  const int aldsb = ((w < 4) ? 0 : 8192) + ((w >> 1) & 1) * 4096 + (w & 1) * 512;

  // ds_read precompute (swizzled slot: wanted kslot = lane>>4, swz=(row>>1)&3=(lane>>1)&3)
  const int aslot8 = (((lane >> 4) ^ ((lane >> 1) & 3)) << 3);
  const int ardA = wr * 4096 + rlow * 32 + aslot8;           // As_h-relative
  const int ardB = 16384 + wc * 2048 + rlow * 32 + aslot8;   // buffer-relative

  f32x4 acc[8][4];
#pragma unroll
  for (int m = 0; m < 8; ++m)
#pragma unroll
    for (int n = 0; n < 4; ++n) acc[m][n] = (f32x4){0.f, 0.f, 0.f, 0.f};
  bf16x8 bhf[4], blf[4];

  // prologue: stage K-tile 0 into buf0 (order: Bh, Bl, Aq0..Aq3 = 8 loads)
  STAGE_BX(0, Bhg, 16384, 0); STAGE_BX(0, Blg, 24576, 0);
  STAGE_A1(0, 0, 0); STAGE_A1(0, 1, 0); STAGE_A1(0, 2, 0); STAGE_A1(0, 3, 0);

  const int NIT = (int)(Ksz / 64);
  for (int t = 0; t < NIT - 1; ++t) {
    const int k1 = t * 64 + 32;   // buf1 <- K-tile 2t+1 (read ph4-7 this iter)
    const int k2 = t * 64 + 64;   // buf0 <- K-tile 2t+2 (read ph0-3 next iter)
    VMW(3); BARR(); LOAD_B(0); PH_A(0, 0, STAGE_BX(1, Bhg, 16384, k1);)
    VMW(4); BARR();            PH_A(0, 1, STAGE_BX(1, Blg, 24576, k1);)
    VMW(5); BARR();            PH_A(0, 2, STAGE_A1(1, 0, k1); STAGE_A1(1, 1, k1);)
    VMW(6); BARR();            PH_A(0, 3, STAGE_A1(1, 2, k1); STAGE_A1(1, 3, k1);)
    VMW(3); BARR(); LOAD_B(1); PH_A(1, 0, STAGE_BX(0, Bhg, 16384, k2);)
    VMW(4); BARR();            PH_A(1, 1, STAGE_BX(0, Blg, 24576, k2);)
    VMW(5); BARR();            PH_A(1, 2, STAGE_A1(0, 0, k2); STAGE_A1(0, 1, k2);)
    VMW(6); BARR();            PH_A(1, 3, STAGE_A1(0, 2, k2); STAGE_A1(0, 3, k2);)
  }
  { // final iter: stage buf1 (K-tile NT-1) normally; no buf0 stages; drain
    const int k1 = (NIT - 1) * 64 + 32;
    VMW(3); BARR(); LOAD_B(0); PH_A(0, 0, STAGE_BX(1, Bhg, 16384, k1);)
    VMW(4); BARR();            PH_A(0, 1, STAGE_BX(1, Blg, 24576, k1);)
    VMW(5); BARR();            PH_A(0, 2, STAGE_A1(1, 0, k1); STAGE_A1(1, 1, k1);)
    VMW(6); BARR();            PH_A(0, 3, STAGE_A1(1, 2, k1); STAGE_A1(1, 3, k1);)
    VMW(3); BARR(); LOAD_B(1); PH_A(1, 0, )
    VMW(2); BARR();            PH_A(1, 1, )
    VMW(1); BARR();            PH_A(1, 2, )
    VMW(0); BARR();            PH_A(1, 3, )
  }

  // epilogue: bias + SiLU + hi/lo split store
#pragma unroll
  for (int m = 0; m < 8; ++m)
#pragma unroll
    for (int n = 0; n < 4; ++n)
#pragma unroll
      for (int j = 0; j < 4; ++j) {
        const int rg = rowA0 + wr * 128 + m * 16 + (lane >> 4) * 4 + j;
        const int cg = rowB0 + wc * 64 + n * 16 + rlow;
        const float v = acc[m][n][j] + b1[cg];
        const float s = v / (1.f + __expf(-v));
        const size_t o = (size_t)rg * C4_ + cg;
        const u16 hi = f2bf(s);
        hh[o] = hi;
        hl[o] = f2bf(s - bf2f(hi));
      }
}

// ============ 128x128 split-bf16 mainloop (R2-verified) for GEMM2 =========
__device__ __forceinline__ void mfma_mainloop(
    const u16* __restrict__ Ah, const u16* __restrict__ Al,
    const u16* __restrict__ Bh, const u16* __restrict__ Bl,
    int K, int rowA0, int rowB0, u16* lds, f32x4 acc[4][4]) {
  const int tid = threadIdx.x;
  const int lane = tid & 63;
  const int w = tid >> 6;
  const int wr = w >> 1, wc = w & 1;

  u16* As_h = lds;            // [128][64]
  u16* As_l = lds + 8192;
  u16* Bs_h = lds + 16384;
  u16* Bs_l = lds + 24576;

#pragma unroll
  for (int m = 0; m < 4; ++m)
#pragma unroll
    for (int n = 0; n < 4; ++n) acc[m][n] = (f32x4){0.f, 0.f, 0.f, 0.f};

  const int rstage = w * 8 + (lane >> 3);
  const int estage = (((lane & 7) ^ (lane >> 3)) << 3);

  for (int k0 = 0; k0 < K; k0 += 64) {
#pragma unroll
    for (int c = 0; c < 4; ++c) {
      const int r = c * 32 + rstage;
      const size_t ga = (size_t)(rowA0 + r) * K + (k0 + estage);
      const size_t gb = (size_t)(rowB0 + r) * K + (k0 + estage);
      const int lo = (c * 32 + w * 8) * 64;
      load_lds16(Ah + ga, As_h + lo);
      load_lds16(Al + ga, As_l + lo);
      load_lds16(Bh + gb, Bs_h + lo);
      load_lds16(Bl + gb, Bs_l + lo);
    }
    __syncthreads();
#pragma unroll
    for (int ks = 0; ks < 2; ++ks) {
      bf16x8 ah[4], al[4], bh[4], bl[4];
      const int kof = (((ks * 4 + (lane >> 4)) ^ (lane & 7)) << 3);
#pragma unroll
      for (int m = 0; m < 4; ++m) {
        const int ra = (wr * 64 + m * 16 + (lane & 15)) * 64 + kof;
        ah[m] = *(const bf16x8*)(As_h + ra);
        al[m] = *(const bf16x8*)(As_l + ra);
      }
#pragma unroll
      for (int n = 0; n < 4; ++n) {
        const int rb = (wc * 64 + n * 16 + (lane & 15)) * 64 + kof;
        bh[n] = *(const bf16x8*)(Bs_h + rb);
        bl[n] = *(const bf16x8*)(Bs_l + rb);
      }
#pragma unroll
      for (int m = 0; m < 4; ++m)
#pragma unroll
        for (int n = 0; n < 4; ++n) {
          acc[m][n] = __builtin_amdgcn_mfma_f32_16x16x32_bf16(ah[m], bh[n], acc[m][n], 0, 0, 0);
          acc[m][n] = __builtin_amdgcn_mfma_f32_16x16x32_bf16(al[m], bh[n], acc[m][n], 0, 0, 0);
          acc[m][n] = __builtin_amdgcn_mfma_f32_16x16x32_bf16(ah[m], bl[n], acc[m][n], 0, 0, 0);
        }
    }
    __syncthreads();
  }
}

// -------- GEMM2: z = h@W2 + b2, write z f32 + bf16 hi ---------------------
__global__ __launch_bounds__(256, 2)
void k_gemm2(const u16* __restrict__ ah, const u16* __restrict__ al,
             const u16* __restrict__ bh, const u16* __restrict__ bl,
             const float* __restrict__ b2,
             float* __restrict__ zf, u16* __restrict__ zh) {
  __shared__ u16 lds[32768];
  const int nbn = C_ / BN;
  const int bm = blockIdx.x / nbn, bn = blockIdx.x % nbn;
  f32x4 acc[4][4];
  mfma_mainloop(ah, al, bh, bl, C4_, bm * BM, bn * BN, lds, acc);
  const int lane = threadIdx.x & 63, w = threadIdx.x >> 6;
  const int wr = w >> 1, wc = w & 1;
#pragma unroll
  for (int m = 0; m < 4; ++m)
#pragma unroll
    for (int n = 0; n < 4; ++n)
#pragma unroll
      for (int j = 0; j < 4; ++j) {
        const int rg = bm * BM + wr * 64 + m * 16 + (lane >> 4) * 4 + j;
        const int cg = bn * BN + wc * 64 + n * 16 + (lane & 15);
        const float v = acc[m][n][j] + b2[cg];
        const size_t o = (size_t)rg * C_ + cg;
        zf[o] = v;
        zh[o] = f2bf(v);
      }
}

// -------- GEMM3 cheap pass: p = z.e (plain bf16, 1 product) --------------
__global__ __launch_bounds__(256, 2)
void k_gemm3c(const u16* __restrict__ zh, const u16* __restrict__ eh,
              u16* __restrict__ dotm) {
  __shared__ u16 lds[16384];
  const int nbn = K_ / BN;
  const int bm = blockIdx.x / nbn, bn = blockIdx.x % nbn;
  const int tid = threadIdx.x, lane = tid & 63, w = tid >> 6;
  const int wr = w >> 1, wc = w & 1;
  f32x4 acc[4][4];
#pragma unroll
  for (int m = 0; m < 4; ++m)
#pragma unroll
    for (int n = 0; n < 4; ++n) acc[m][n] = (f32x4){0.f, 0.f, 0.f, 0.f};

  const int rstage = w * 8 + (lane >> 3);
  const int estage = (((lane & 7) ^ (lane >> 3)) << 3);
  for (int k0 = 0; k0 < C_; k0 += 64) {
#pragma unroll
    for (int c = 0; c < 4; ++c) {
      const int r = c * 32 + rstage;
      const size_t ga = (size_t)(bm * BM + r) * C_ + (k0 + estage);
      const size_t gb = (size_t)(bn * BN + r) * C_ + (k0 + estage);
      const int lo = (c * 32 + w * 8) * 64;
      load_lds16(zh + ga, lds + lo);
      load_lds16(eh + gb, lds + 8192 + lo);
    }
    __syncthreads();
#pragma unroll
    for (int ks = 0; ks < 2; ++ks) {
      bf16x8 ah[4], bh[4];
      const int kof = (((ks * 4 + (lane >> 4)) ^ (lane & 7)) << 3);
#pragma unroll
      for (int m = 0; m < 4; ++m)
        ah[m] = *(const bf16x8*)(lds + (wr * 64 + m * 16 + (lane & 15)) * 64 + kof);
#pragma unroll
      for (int n = 0; n < 4; ++n)
        bh[n] = *(const bf16x8*)(lds + 8192 + (wc * 64 + n * 16 + (lane & 15)) * 64 + kof);
#pragma unroll
      for (int m = 0; m < 4; ++m)
#pragma unroll
        for (int n = 0; n < 4; ++n)
          acc[m][n] = __builtin_amdgcn_mfma_f32_16x16x32_bf16(ah[m], bh[n], acc[m][n], 0, 0, 0);
    }
    __syncthreads();
  }
  u16* outp = lds;  // repack [128][128] f16 for coalesced stores
#pragma unroll
  for (int m = 0; m < 4; ++m)
#pragma unroll
    for (int n = 0; n < 4; ++n)
#pragma unroll
      for (int j = 0; j < 4; ++j) {
        const int rl = wr * 64 + m * 16 + (lane >> 4) * 4 + j;
        const int cl = wc * 64 + n * 16 + (lane & 15);
        outp[rl * 128 + cl] = f2h(acc[m][n][j]);
      }
  __syncthreads();
  const size_t base = (size_t)(bm * BM) * K_ + bn * BN;
  for (int i = tid; i < 128 * 64; i += 256) {
    const int r = i >> 6, c = (i & 63) * 2;
    *(unsigned int*)(dotm + base + (size_t)r * K_ + c) =
        *(const unsigned int*)(outp + r * 128 + c);
  }
}

// -------- scan: per-row min + candidates within rigorous bound ------------
__global__ __launch_bounds__(256)
void k_scan(const u16* __restrict__ dotm, const float* __restrict__ norms,
            const float* __restrict__ zn2, const unsigned int* __restrict__ emaxb,
            int* __restrict__ cand, int* __restrict__ candcnt) {
  __shared__ __align__(16) u16 srow[K_];
  __shared__ float rmin[4];
  __shared__ int lcnt;
  const int r = blockIdx.x, tid = threadIdx.x;
  const size_t base = (size_t)r * K_;
  for (int i = tid; i < K_ / 8; i += 256)
    ((uint4*)srow)[i] = ((const uint4*)(dotm + base))[i];
  if (tid == 0) lcnt = 0;
  __syncthreads();
  float mymin = 3.4e38f;
  for (int k = tid; k < K_; k += 256)
    mymin = fminf(mymin, norms[k] - 2.f * h2f(srow[k]));
#pragma unroll
  for (int off = 32; off >= 1; off >>= 1)
    mymin = fminf(mymin, __shfl_xor(mymin, off, 64));
  if ((tid & 63) == 0) rmin[tid >> 6] = mymin;
  __syncthreads();
  const float gmin = fminf(fminf(rmin[0], rmin[1]), fminf(rmin[2], rmin[3]));
  const float bnd = 0.010f * sqrtf(zn2[r]) * sqrtf(__uint_as_float(*emaxb)) + 0.01f;
  const float win = gmin + 2.f * bnd;
  for (int k = tid; k < K_; k += 256) {
    const float sc = norms[k] - 2.f * h2f(srow[k]);
    if (sc <= win) {
      const int p = atomicAdd(&lcnt, 1);
      if (p < CAP) cand[r * CAP + p] = k;
    }
  }
  __syncthreads();
  if (tid == 0) candcnt[r] = lcnt;
}

// -------- rescore: exact f64 distance over candidates ---------------------
__global__ __launch_bounds__(64)
void k_rescore(const int* __restrict__ cand, const int* __restrict__ candcnt,
               const float* __restrict__ zf, const float* __restrict__ embT,
               int* __restrict__ idx) {
  const int r = blockIdx.x, lane = threadIdx.x;
  const int cnt = candcnt[r];
  if (cnt <= 1) { if (lane == 0) idx[r] = cand[r * CAP]; return; }
  const bool full = cnt > CAP;
  const int n = full ? K_ : cnt;
  double bestd = 1e300; int bestk = 0x7fffffff;
  for (int c = 0; c < n; ++c) {
    const int k = full ? c : cand[r * CAP + c];
    double s = 0.0;
    for (int i = lane; i < C_; i += 64) {
      const double d = (double)zf[(size_t)r * C_ + i] - (double)embT[(size_t)k * C_ + i];
      s += d * d;
    }
#pragma unroll
    for (int off = 32; off >= 1; off >>= 1) s += __shfl_xor(s, off, 64);
    if (s < bestd || (s == bestd && k < bestk)) { bestd = s; bestk = k; }
  }
  if (lane == 0) idx[r] = bestk;
}

// -------- prep kernels ----------------------------------------------------
__global__ void k_split(const float4* __restrict__ in, size_t n4,
                        u16* __restrict__ hi, u16* __restrict__ lo) {
  size_t i = (size_t)blockIdx.x * blockDim.x + threadIdx.x;
  const size_t stride = (size_t)gridDim.x * blockDim.x;
  for (; i < n4; i += stride) {
    const float4 v = in[i];
    const float vv[4] = {v.x, v.y, v.z, v.w};
    u16x4 h, l;
#pragma unroll
    for (int j = 0; j < 4; ++j) {
      const u16 a = f2bf(vv[j]);
      h[j] = a;
      l[j] = f2bf(vv[j] - bf2f(a));
    }
    *(u16x4*)(hi + i * 4) = h;
    *(u16x4*)(lo + i * 4) = l;
  }
}

template <bool WF32, bool WLO>
__global__ void k_tsplit(const float* __restrict__ in, int R, int Cc,
                         u16* __restrict__ hiT, u16* __restrict__ loT,
                         float* __restrict__ f32T) {
  __shared__ float t[32][33];
  const int c0 = blockIdx.x * 32, r0 = blockIdx.y * 32;
  const int tx = threadIdx.x, ty = threadIdx.y;
#pragma unroll
  for (int i = 0; i < 4; ++i)
    t[ty + i * 8][tx] = in[(size_t)(r0 + ty + i * 8) * Cc + (c0 + tx)];
  __syncthreads();
#pragma unroll
  for (int i = 0; i < 4; ++i) {
    const int orow = c0 + ty + i * 8;
    const int ocol = r0 + tx;
    const float v = t[tx][ty + i * 8];
    const size_t o = (size_t)orow * R + ocol;
    const u16 hi = f2bf(v);
    hiT[o] = hi;
    if (WLO) loT[o] = f2bf(v - bf2f(hi));
    if (WF32) f32T[o] = v;
  }
}

__global__ __launch_bounds__(256)
void k_rownorm(const float* __restrict__ in, float* __restrict__ out,
               unsigned int* __restrict__ maxb, int domax) {
  const int r = blockIdx.x, tid = threadIdx.x;
  const float4 v = *(const float4*)(in + (size_t)r * 1024 + tid * 4);
  double s = (double)v.x * v.x + (double)v.y * v.y +
             (double)v.z * v.z + (double)v.w * v.w;
#pragma unroll
  for (int off = 32; off >= 1; off >>= 1) s += __shfl_xor(s, off, 64);
  __shared__ double sw[4];
  if ((tid & 63) == 0) sw[tid >> 6] = s;
  __syncthreads();
  if (tid == 0) {
    const float t = (float)(sw[0] + sw[1] + sw[2] + sw[3]);
    out[r] = t;
    if (domax) atomicMax(maxb, __float_as_uint(t));
  }
}

__global__ void k_init(double* __restrict__ dacc, unsigned int* __restrict__ emaxb) {
  *dacc = 0.0;
  *emaxb = 0u;
}

// -------- finalize: gather + LayerNorm + commitment partial ---------------
__global__ __launch_bounds__(256)
void k_finalize(const int* __restrict__ idx,
                const float* __restrict__ embT, const float* __restrict__ zf,
                const float* __restrict__ gamma, const float* __restrict__ beta,
                float* __restrict__ out, double* __restrict__ dacc) {
  const int row = blockIdx.x;
  const int tid = threadIdx.x;
  const int lane = tid & 63, w = tid >> 6;
  const int id = idx[row];

  const float4 e4 = *(const float4*)(embT + (size_t)id * C_ + tid * 4);
  float s1 = e4.x + e4.y + e4.z + e4.w;
  float s2 = e4.x * e4.x + e4.y * e4.y + e4.z * e4.z + e4.w * e4.w;
#pragma unroll
  for (int off = 32; off >= 1; off >>= 1) {
    s1 += __shfl_xor(s1, off, 64);
    s2 += __shfl_xor(s2, off, 64);
  }
  __shared__ float r1[4], r2[4], rd[4];
  if (lane == 0) { r1[w] = s1; r2[w] = s2; }
  __syncthreads();
  const float S1 = r1[0] + r1[1] + r1[2] + r1[3];
  const float S2 = r2[0] + r2[1] + r2[2] + r2[3];
  const float mu = S1 * (1.f / C_);
  const float var = S2 * (1.f / C_) - mu * mu;
  const float inv = 1.f / sqrtf(var + 1e-5f);

  const float4 z4 = *(const float4*)(zf + (size_t)row * C_ + tid * 4);
  const float4 g4 = *(const float4*)(gamma + tid * 4);
  const float4 b4 = *(const float4*)(beta + tid * 4);
  float4 o4;
  o4.x = (e4.x - mu) * inv * g4.x + b4.x;
  o4.y = (e4.y - mu) * inv * g4.y + b4.y;
  o4.z = (e4.z - mu) * inv * g4.z + b4.z;
  o4.w = (e4.w - mu) * inv * g4.w + b4.w;
  *(float4*)(out + (size_t)row * C_ + tid * 4) = o4;

  const float dx = e4.x - z4.x, dy = e4.y - z4.y, dz = e4.z - z4.z, dw = e4.w - z4.w;
  float d = dx * dx + dy * dy + dz * dz + dw * dw;
#pragma unroll
  for (int off = 32; off >= 1; off >>= 1) d += __shfl_xor(d, off, 64);
  __syncthreads();
  if (lane == 0) rd[w] = d;
  __syncthreads();
  if (tid == 0) atomicAdd(dacc, (double)(rd[0] + rd[1] + rd[2] + rd[3]));
}

__global__ void k_wdiff(const double* __restrict__ dacc, float* __restrict__ out) {
  out[(size_t)B_ * C_] = (float)(0.01 * (*dacc) / ((double)B_ * (double)C_));
}

// ---------------------------------------------------------------------------
extern "C" void kernel_launch(void* const* d_in, const int* in_sizes, int n_in,
                              void* d_out, int out_size, void* d_ws, size_t ws_size,
                              hipStream_t stream) {
  const float* x     = (const float*)d_in[0];
  const float* W1    = (const float*)d_in[1];
  const float* b1    = (const float*)d_in[2];
  const float* W2    = (const float*)d_in[3];
  const float* b2    = (const float*)d_in[4];
  const float* gamma = (const float*)d_in[5];
  const float* beta  = (const float*)d_in[6];
  const float* embed = (const float*)d_in[7];
  float* out = (float*)d_out;

  char* ws = (char*)d_ws;
  const size_t M = 1048576ull;
  u16* xh  = (u16*)(ws);
  u16* xl  = (u16*)(ws + 64 * M);
  u16* w1h = (u16*)(ws + 128 * M);
  u16* w1l = (u16*)(ws + 160 * M);
  u16* hh  = (u16*)(ws + 192 * M);
  u16* hl  = (u16*)(ws + 256 * M);
  u16* w2h = (u16*)(ws);
  u16* w2l = (u16*)(ws + 8 * M);
  float* zf = (float*)(ws + 16 * M);
  u16* zh  = (u16*)(ws + 48 * M);
  float* embT = (float*)(ws + 64 * M);
  u16* eh  = (u16*)(ws + 96 * M);
  float* norms = (float*)(ws + 112 * M);
  float* zn2   = (float*)(ws + 112 * M + 65536ull);
  int* candcnt = (int*)(ws + 112 * M + 131072ull);
  int* idx     = (int*)(ws + 112 * M + 196608ull);
  unsigned int* emaxb = (unsigned int*)(ws + 112 * M + 262144ull);
  double* dacc = (double*)(ws + 112 * M + 262144ull + 64ull);
  int* cand    = (int*)(ws + 113 * M);
  u16* dotm    = (u16*)(ws + 192 * M);

  (void)hipFuncSetAttribute((const void*)k_gemm1,
                            hipFuncAttributeMaxDynamicSharedMemorySize, 131072);

  // 1. split x -> xh/xl
  k_split<<<2048, 256, 0, stream>>>((const float4*)x, (size_t)B_ * D_ / 4, xh, xl);
  // 2. W1 [D][4C] -> W1T hi/lo [4C][D]
  k_tsplit<false, true><<<dim3(C4_ / 32, D_ / 32), dim3(32, 8), 0, stream>>>(W1, D_, C4_, w1h, w1l, nullptr);
  // 3. GEMM1 (256^2 8-phase; +bias+SiLU+split)
  k_gemm1<<<(B_ / 256) * (C4_ / 256), 512, 131072, stream>>>(xh, xl, w1h, w1l, b1, hh, hl);
  // 4. W2 [4C][C] -> W2T hi/lo [C][4C]
  k_tsplit<false, true><<<dim3(C_ / 32, C4_ / 32), dim3(32, 8), 0, stream>>>(W2, C4_, C_, w2h, w2l, nullptr);
  // 5. GEMM2 (+bias, write z f32 + bf16 hi)
  k_gemm2<<<(B_ / BM) * (C_ / BN), 256, 0, stream>>>(hh, hl, w2h, w2l, b2, zf, zh);
  // 6. embed [C][K] -> embT f32 + bf16 hi [K][C]
  k_tsplit<true, false><<<dim3(K_ / 32, C_ / 32), dim3(32, 8), 0, stream>>>(embed, C_, K_, eh, nullptr, embT);
  // 7. init accumulators
  k_init<<<1, 1, 0, stream>>>(dacc, emaxb);
  // 8. norms (coalesced, f64) + max; z row norms
  k_rownorm<<<K_, 256, 0, stream>>>(embT, norms, emaxb, 1);
  k_rownorm<<<B_, 256, 0, stream>>>(zf, zn2, emaxb, 0);
  // 9. cheap 1-product dot matrix
  k_gemm3c<<<(B_ / BM) * (K_ / BN), 256, 0, stream>>>(zh, eh, dotm);
  // 10. per-row min + candidate window
  k_scan<<<B_, 256, 0, stream>>>(dotm, norms, zn2, emaxb, cand, candcnt);
  // 11. exact f64 rescore -> final indices
  k_rescore<<<B_, 64, 0, stream>>>(cand, candcnt, zf, embT, idx);
  // 12. gather + LayerNorm + commitment
  k_finalize<<<B_, 256, 0, stream>>>(idx, embT, zf, gamma, beta, out, dacc);
  // 13. scalar diff output
  k_wdiff<<<1, 1, 0, stream>>>(dacc, out);
}